// Round 4
// baseline (498.639 us; speedup 1.0000x reference)
//
#include <hip/hip_runtime.h>
#include <hip/hip_bf16.h>

#define NN 1024
#define HID 128
#define NHEADS 4
#define HDD 32
#define NL 3
#define NBLK 256     // k_main grid = one block per CU
#define TI 4         // i-rows per block

// ---- ws layout (float-word units) ----
constexpr int OFF_CONV = 16;
constexpr int OFF_NF   = OFF_CONV;            // 3072
constexpr int OFF_WP   = OFF_NF  + 3072;      // 384
constexpr int OFF_BP   = OFF_WP  + 384;       // 128
constexpr int OFF_WL   = OFF_BP  + 128;       // 49152
constexpr int OFF_WR   = OFF_WL  + 49152;     // 49152
constexpr int OFF_WVW  = OFF_WR  + 49152;     // 49152
constexpr int OFF_ATT  = OFF_WVW + 49152;     // 96
constexpr int OFF_GAM  = OFF_ATT + 96;        // 384
constexpr int OFF_BET  = OFF_GAM + 384;       // 384
constexpr int OFF_WN1  = OFF_BET + 384;       // 8192
constexpr int OFF_BN1  = OFF_WN1 + 8192;      // 64
constexpr int OFF_WN2  = OFF_BN1 + 64;        // 64
constexpr int OFF_BN2  = OFF_WN2 + 64;        // 1
constexpr int OFF_WD1  = OFF_BN2 + 1;         // 8192
constexpr int OFF_BD1  = OFF_WD1 + 8192;      // 64
constexpr int OFF_WD2  = OFF_BD1 + 64;        // 128
constexpr int OFF_BD2  = OFF_WD2 + 128;       // 2
constexpr int OFF_WV1  = OFF_BD2 + 2;         // 8192
constexpr int OFF_BV1  = OFF_WV1 + 8192;      // 64
constexpr int OFF_WV2  = OFF_BV1 + 64;        // 64
constexpr int OFF_BV2  = OFF_WV2 + 64;        // 1
constexpr int OFF_CONV_END = OFF_BV2 + 1;
constexpr int CONV_TOTAL = OFF_CONV_END - OFF_CONV;
constexpr int OFF_MASK = 176960;              // 1024*32 uint32 words
constexpr int OFF_H    = OFF_MASK + NN*32;
constexpr int OFF_WLH  = OFF_H   + NN*HID;
constexpr int OFF_WRH  = OFF_WLH + NN*HID;
constexpr int OFF_WVH  = OFF_WRH + NN*HID;
constexpr int OFF_POOL = OFF_WVH + NN*HID;    // 128 floats
constexpr int OFF_CNT  = OFF_POOL + HID;      // barrier counter (u32)
constexpr int OFF_GEN  = OFF_CNT + 1;         // barrier generation (u32)

__device__ __forceinline__ float bf2f(unsigned short u) {
    return __uint_as_float(((unsigned)u) << 16);
}
__device__ __forceinline__ float ldf(const void* p, int idx, bool bf) {
    return bf ? bf2f(((const unsigned short*)p)[idx]) : ((const float*)p)[idx];
}
__device__ __forceinline__ void store_out(void* out, int idx, float v, bool bf) {
    if (bf) {
        unsigned u = __float_as_uint(v);
        unsigned r = (u + 0x7FFFu + ((u >> 16) & 1u)) >> 16;
        ((unsigned short*)out)[idx] = (unsigned short)r;
    } else {
        ((float*)out)[idx] = v;
    }
}
// per-wave dtype sniff: fp32 normals have exponent field in [110,140];
// packed bf16 pairs viewed as fp32 essentially never do. Call from ALL lanes.
__device__ __forceinline__ bool detect_bf(const unsigned* nf) {
    unsigned w = nf[threadIdx.x & 63];
    int e = (int)((w >> 23) & 0xFFu);
    unsigned long long b = __ballot(e >= 110 && e <= 140);
    return __popcll(b) < 32;
}

struct P21 { const void* p[21]; };
__device__ const int g_sizes[21] = {3072,384,128,49152,49152,49152,96,384,384,
                                    8192,64,64,1,8192,64,128,2,8192,64,64,1};
__device__ const int g_dsts[21] = {OFF_NF,OFF_WP,OFF_BP,OFF_WL,OFF_WR,OFF_WVW,OFF_ATT,
                                   OFF_GAM,OFF_BET,OFF_WN1,OFF_BN1,OFF_WN2,OFF_BN2,
                                   OFF_WD1,OFF_BD1,OFF_WD2,OFF_BD2,OFF_WV1,OFF_BV1,
                                   OFF_WV2,OFF_BV2};

// ---- setup: zero barrier/pool + convert params + adj->bitmask + h0 ----
__global__ __launch_bounds__(256) void k_setup(P21 in, const void* adj, const unsigned* nf,
                                               float* ws) {
    bool bf = detect_bf(nf);
    int b = blockIdx.x, t = threadIdx.x;
    int gid = b * 256 + t;

    if (b == 0 && t < HID + 2) ws[OFF_POOL + t] = 0.0f;  // pooled + cnt + gen

    if (gid < CONV_TOTAL) {
        int rem = gid, s = 0;
        while (s < 21 && rem >= g_sizes[s]) { rem -= g_sizes[s]; s++; }
        if (s < 21) ws[g_dsts[s] + rem] = ldf(in.p[s], rem, bf);
    }

    // adjacency row b -> 32 packed words
    unsigned* mask = (unsigned*)(ws + OFF_MASK);
    int lane = t & 63, wv = t >> 6;
    for (int p = 0; p < 4; p++) {
        int j = p * 256 + t;
        float v = ldf(adj, b * NN + j, bf);
        unsigned long long bl = __ballot(v > 0.5f);
        if (lane == 0) {
            mask[b * 32 + p * 8 + wv * 2]     = (unsigned)bl;
            mask[b * 32 + p * 8 + wv * 2 + 1] = (unsigned)(bl >> 32);
        }
    }

    // h0 row b = relu(nf @ Wp + bp)  (raw inputs, bf-branch)
    if (t < HID) {
        float a = ldf(in.p[2], t, bf);  // bp
        #pragma unroll
        for (int k = 0; k < 3; k++)
            a += ldf(in.p[0], b * 3 + k, bf) * ldf(in.p[1], k * HID + t, bf);
        ws[OFF_H + b * HID + t] = fmaxf(a, 0.0f);
    }
}

// ---- device-scope grid barrier (generation-counted) ----
__device__ __forceinline__ void gridbar(float* ws) {
    __syncthreads();
    if (threadIdx.x == 0) {
        unsigned* cnt = (unsigned*)(ws + OFF_CNT);
        unsigned* gen = (unsigned*)(ws + OFF_GEN);
        __threadfence();
        unsigned g = __hip_atomic_load(gen, __ATOMIC_ACQUIRE, __HIP_MEMORY_SCOPE_AGENT);
        unsigned a = __hip_atomic_fetch_add(cnt, 1u, __ATOMIC_ACQ_REL, __HIP_MEMORY_SCOPE_AGENT);
        if (a == NBLK - 1) {
            __hip_atomic_store(cnt, 0u, __ATOMIC_RELAXED, __HIP_MEMORY_SCOPE_AGENT);
            __hip_atomic_fetch_add(gen, 1u, __ATOMIC_RELEASE, __HIP_MEMORY_SCOPE_AGENT);
        } else {
            while (__hip_atomic_load(gen, __ATOMIC_ACQUIRE, __HIP_MEMORY_SCOPE_AGENT) == g)
                __builtin_amdgcn_s_sleep(8);
        }
        __threadfence();
    }
    __syncthreads();
}

// ---- fused main: 3 x (mm3 -> attn+LN+residual) -> heads -> pooled -> value ----
// grid 256 blocks x 256 thr; block handles i0..i0+3; wave = head.
// VGPR use (acc[4][32]+wl[4][32]+att[32] > 256) forces 1 wave/SIMD => exactly
// 1 block/CU => all 256 blocks co-resident => gridbar is deadlock-free.
__global__ __launch_bounds__(256, 1) void k_main(const unsigned* nf, float* ws, void* out) {
    bool bf = detect_bf(nf);
    int t = threadIdx.x;
    int lane = t & 63;
    int i0 = blockIdx.x * TI;

    __shared__ float hs[TI * HID];
    __shared__ unsigned mrow[TI * 32];
    __shared__ float agg_s[TI * HID];

    for (int l = 0; l < NL; l++) {
        // ---- mm3: rows i0..i0+3 of wlh/wrh/wvh ----
        for (int q = t; q < TI * HID; q += 256) hs[q] = ws[OFF_H + i0 * HID + q];
        __syncthreads();
        for (int task = t; task < 3 * HID; task += 256) {
            int m = task >> 7, c = task & 127;
            const float* W = ws + ((m == 0) ? OFF_WL : (m == 1) ? OFF_WR : OFF_WVW) + l * HID * HID;
            float a0 = 0, a1 = 0, a2 = 0, a3 = 0;
            #pragma unroll 4
            for (int k = 0; k < HID; k++) {
                float w = W[k * HID + c];
                a0 = fmaf(hs[0 * HID + k], w, a0);
                a1 = fmaf(hs[1 * HID + k], w, a1);
                a2 = fmaf(hs[2 * HID + k], w, a2);
                a3 = fmaf(hs[3 * HID + k], w, a3);
            }
            int doff = (m == 0) ? OFF_WLH : (m == 1) ? OFF_WRH : OFF_WVH;
            ws[doff + (i0 + 0) * HID + c] = a0;
            ws[doff + (i0 + 1) * HID + c] = a1;
            ws[doff + (i0 + 2) * HID + c] = a2;
            ws[doff + (i0 + 3) * HID + c] = a3;
        }
        gridbar(ws);   // all wlh/wrh/wvh visible device-wide

        // ---- attention: wave = head h, 4 i's, lane = j within 64-chunk ----
        int h = __builtin_amdgcn_readfirstlane(t >> 6);
        if (t < TI * 32) mrow[t] = ((const unsigned*)(ws + OFF_MASK))[(i0 + (t >> 5)) * 32 + (t & 31)];
        __syncthreads();

        float att_r[32], wlr[TI][32], cl[TI];
        {
            const float* attp = ws + OFF_ATT + l * HDD;
            #pragma unroll
            for (int d = 0; d < 32; d++) att_r[d] = attp[d];
            #pragma unroll
            for (int i = 0; i < TI; i++) {
                const float* wp = ws + OFF_WLH + (i0 + i) * HID + h * HDD;
                float c = 0.0f;
                #pragma unroll
                for (int d = 0; d < 32; d++) { wlr[i][d] = wp[d]; c = fmaf(att_r[d], wlr[i][d], c); }
                cl[i] = c;
            }
        }

        const float* wrb = ws + OFF_WRH + h * HDD;
        const float* wvb = ws + OFF_WVH + h * HDD;
        float acc[TI][32];
        float lsum[TI] = {0, 0, 0, 0};
        #pragma unroll
        for (int i = 0; i < TI; i++)
            #pragma unroll
            for (int d = 0; d < 32; d++) acc[i][d] = 0.0f;

        #pragma unroll 1
        for (int jc = 0; jc < 16; jc++) {
            int j = jc * 64 + lane;
            const float* wr = wrb + j * HID;
            const float* wv = wvb + j * HID;
            float4 r[8], v[8];
            #pragma unroll
            for (int c = 0; c < 8; c++) r[c] = *(const float4*)(wr + c * 4);
            #pragma unroll
            for (int c = 0; c < 8; c++) v[c] = *(const float4*)(wv + c * 4);

            float cr = 0.0f, tt[TI] = {0, 0, 0, 0};
            #pragma unroll
            for (int c = 0; c < 8; c++) {
                const float rv[4] = {r[c].x, r[c].y, r[c].z, r[c].w};
                #pragma unroll
                for (int k = 0; k < 4; k++) {
                    int d = c * 4 + k;
                    cr = fmaf(att_r[d], rv[k], cr);
                    #pragma unroll
                    for (int i = 0; i < TI; i++) {
                        float y = wlr[i][d] + rv[k];
                        tt[i] = fmaf(att_r[d], fabsf(y), tt[i]);
                    }
                }
            }
            #pragma unroll
            for (int i = 0; i < TI; i++) {
                unsigned w = mrow[i * 32 + jc * 2 + (lane >> 5)];
                float act = (float)((w >> (lane & 31)) & 1u);
                float e = fminf(0.6f * (cl[i] + cr) + 0.4f * tt[i], 80.0f);
                float pe = act * __expf(e);   // exp(e) w/o max-sub: |e| small by norm bound
                lsum[i] += pe;
                #pragma unroll
                for (int c = 0; c < 8; c++) {
                    acc[i][c * 4 + 0] = fmaf(pe, v[c].x, acc[i][c * 4 + 0]);
                    acc[i][c * 4 + 1] = fmaf(pe, v[c].y, acc[i][c * 4 + 1]);
                    acc[i][c * 4 + 2] = fmaf(pe, v[c].z, acc[i][c * 4 + 2]);
                    acc[i][c * 4 + 3] = fmaf(pe, v[c].w, acc[i][c * 4 + 3]);
                }
            }
        }

        // wave all-reduce of acc + lsum
        #pragma unroll
        for (int off = 32; off > 0; off >>= 1) {
            #pragma unroll
            for (int i = 0; i < TI; i++) {
                lsum[i] += __shfl_xor(lsum[i], off, 64);
                #pragma unroll
                for (int d = 0; d < 32; d++) acc[i][d] += __shfl_xor(acc[i][d], off, 64);
            }
        }
        if (lane == 0) {
            #pragma unroll
            for (int i = 0; i < TI; i++) {
                float inv = 1.0f / lsum[i];
                #pragma unroll
                for (int d = 0; d < 32; d++) agg_s[i * HID + h * HDD + d] = acc[i][d] * inv;
            }
        }
        __syncthreads();

        // ---- LN + relu + residual: wave iw handles node i0+iw, lane -> {c, c+64} ----
        {
            int iw = t >> 6;
            int i = i0 + iw;
            float a1 = agg_s[iw * HID + lane];
            float a2 = agg_s[iw * HID + 64 + lane];
            float s = a1 + a2, s2 = a1 * a1 + a2 * a2;
            #pragma unroll
            for (int off = 32; off > 0; off >>= 1) {
                s  += __shfl_xor(s,  off, 64);
                s2 += __shfl_xor(s2, off, 64);
            }
            float mu  = s  * (1.0f / HID);
            float var = s2 * (1.0f / HID) - mu * mu;
            float rs = rsqrtf(var + 1e-5f);
            float o1 = (a1 - mu) * rs * ws[OFF_GAM + l * HID + lane]      + ws[OFF_BET + l * HID + lane];
            float o2 = (a2 - mu) * rs * ws[OFF_GAM + l * HID + 64 + lane] + ws[OFF_BET + l * HID + 64 + lane];
            ws[OFF_H + i * HID + lane]      += fmaxf(o1, 0.0f);
            ws[OFF_H + i * HID + 64 + lane] += fmaxf(o2, 0.0f);
        }
        gridbar(ws);   // updated h visible device-wide
    }

    // ---- heads: wave iw -> node i0+iw, lane = hidden unit ----
    {
        int iw = t >> 6;
        int i = i0 + iw;
        float z1 = ws[OFF_BN1 + lane], zd = ws[OFF_BD1 + lane];
        const float* Wn1 = ws + OFF_WN1;
        const float* Wd1 = ws + OFF_WD1;
        #pragma unroll 4
        for (int k = 0; k < HID; k++) {
            float hk = ws[OFF_H + i * HID + k];
            z1 = fmaf(hk, Wn1[k * 64 + lane], z1);
            zd = fmaf(hk, Wd1[k * 64 + lane], zd);
        }
        z1 = fmaxf(z1, 0.0f); zd = fmaxf(zd, 0.0f);
        float lg = z1 * ws[OFF_WN2 + lane];
        float d0 = zd * ws[OFF_WD2 + lane * 2 + 0];
        float d1 = zd * ws[OFF_WD2 + lane * 2 + 1];
        #pragma unroll
        for (int off = 32; off > 0; off >>= 1) {
            lg += __shfl_xor(lg, off, 64);
            d0 += __shfl_xor(d0, off, 64);
            d1 += __shfl_xor(d1, off, 64);
        }
        if (lane == 0) {
            store_out(out, i,              lg + ws[OFF_BN2],     bf);
            store_out(out, NN + i * 2 + 0, d0 + ws[OFF_BD2 + 0], bf);
            store_out(out, NN + i * 2 + 1, d1 + ws[OFF_BD2 + 1], bf);
        }
    }

    // ---- pooled mean partials + value head ----
    if (t < HID) {
        float s = 0.0f;
        #pragma unroll
        for (int r = 0; r < TI; r++) s += ws[OFF_H + (i0 + r) * HID + t];
        atomicAdd(&ws[OFF_POOL + t], s);
    }
    gridbar(ws);
    if (blockIdx.x == 0 && t < 64) {
        float z = ws[OFF_BV1 + t];
        #pragma unroll 4
        for (int k = 0; k < HID; k++)
            z = fmaf(ws[OFF_POOL + k] * (1.0f / NN), ws[OFF_WV1 + k * 64 + t], z);
        z = fmaxf(z, 0.0f);
        float pv = z * ws[OFF_WV2 + t];
        #pragma unroll
        for (int off = 32; off > 0; off >>= 1) pv += __shfl_xor(pv, off, 64);
        if (t == 0) store_out(out, 3072, pv + ws[OFF_BV2], bf);
    }
}

extern "C" void kernel_launch(void* const* d_in, const int* in_sizes, int n_in,
                              void* d_out, int out_size, void* d_ws, size_t ws_size,
                              hipStream_t stream) {
    float* ws = (float*)d_ws;
    const unsigned* nf = (const unsigned*)d_in[0];

    P21 ptrs;
    const int map[21] = {0,2,3,4,5,6,7,8,9,10,11,12,13,14,15,16,17,18,19,20,21};
    for (int s = 0; s < 21; s++) ptrs.p[s] = d_in[map[s]];

    k_setup<<<NN, 256, 0, stream>>>(ptrs, d_in[1], nf, ws);
    k_main<<<NBLK, 256, 0, stream>>>(nf, ws, d_out);
}